// Round 6
// baseline (463.021 us; speedup 1.0000x reference)
//
#include <hip/hip_runtime.h>
#include <math.h>

typedef __bf16 bf16;
typedef __bf16 bf16x8 __attribute__((ext_vector_type(8)));
typedef __bf16 bf16x4 __attribute__((ext_vector_type(4)));
typedef float  f32x4  __attribute__((ext_vector_type(4)));

namespace {
constexpr int B_ = 2, S_ = 2048, HID_ = 1024, H_ = 16, D_ = 64, R_ = 128, NREL_ = 257;
constexpr float LOG2E_ = 1.44269504f;
constexpr float QSC_ = 0.125f * LOG2E_;   // 1/sqrt(D) and log2(e), folded into Q
}

static __device__ __forceinline__ f32x4 mfma16(bf16x8 a, bf16x8 b, f32x4 c) {
  return __builtin_amdgcn_mfma_f32_16x16x32_bf16(a, b, c, 0, 0, 0);
}
static __device__ __forceinline__ void split2(float f, bf16 &hi, bf16 &lo) {
  hi = (bf16)f; lo = (bf16)(f - (float)hi);
}

// ---------------- prep: scaled mask, rkE*8 -> bf16 [272][64], rvE^T -> bf16 [64][288]
__global__ void prep_kernel(const float* __restrict__ st_mask,
                            const float* __restrict__ rkE, const float* __restrict__ rvE,
                            float* __restrict__ msk2, bf16* __restrict__ rkEb,
                            bf16* __restrict__ rvTb)
{
  const int t0 = blockIdx.x * 256 + threadIdx.x;
  const int NT = gridDim.x * 256;
  for (int t = t0; t < B_ * S_; t += NT)
    msk2[t] = (1.f - st_mask[t]) * -10000.f * LOG2E_;
  for (int t = t0; t < 272 * 64; t += NT) {
    const int bk = t >> 6, d = t & 63;
    rkEb[t] = (bk < NREL_) ? (bf16)(rkE[bk * D_ + d] * 8.0f) : (bf16)0.f;
  }
  for (int t = t0; t < 64 * 288; t += NT) {
    const int d = t / 288, c = t - d * 288;
    rvTb[t] = (c < NREL_) ? (bf16)rvE[c * D_ + d] : (bf16)0.f;
  }
}

// ---------------- merged QKV projection, split-bf16 MFMA, 128x64 tile.
// V written TILED: [B,H, S/32, D, 32] so PV fragment loads are dense.
__global__ __launch_bounds__(256, 3) void qkv_mfma_kernel(
    const float* __restrict__ A,
    const float* __restrict__ Wq, const float* __restrict__ bq,
    const float* __restrict__ Wk, const float* __restrict__ bk,
    const float* __restrict__ Wv, const float* __restrict__ bv,
    bf16* __restrict__ Qh, bf16* __restrict__ Ql,
    bf16* __restrict__ Kb, bf16* __restrict__ Vt)
{
  const int n0 = blockIdx.x * 64;
  const int m0 = blockIdx.y * 128;
  const int tid = threadIdx.x;
  const int l = tid & 63, w = tid >> 6;
  const int cl = l & 15, g = l >> 4, kg8 = g * 8;

  __shared__ __align__(16) bf16 Ah[128][40], Al[128][40];
  __shared__ __align__(16) bf16 Bh[3][64][40], Bl[3][64][40];

  f32x4 acc[2][3][4];
#pragma unroll
  for (int hf = 0; hf < 2; ++hf)
#pragma unroll
    for (int s = 0; s < 3; ++s)
#pragma unroll
      for (int nf = 0; nf < 4; ++nf)
#pragma unroll
        for (int i = 0; i < 4; ++i) acc[hf][s][nf][i] = 0.f;

  const int srow = tid >> 2, sk = (tid & 3) * 8;
  const float* Ws_[3] = {Wq, Wk, Wv};

  for (int kt = 0; kt < HID_ / 32; ++kt) {
#pragma unroll
    for (int hf = 0; hf < 2; ++hf) {
      const float* ap = A + (size_t)(m0 + hf * 64 + srow) * HID_ + kt * 32 + sk;
      const float4 a0 = *(const float4*)ap, a1 = *(const float4*)(ap + 4);
      const float av[8] = {a0.x,a0.y,a0.z,a0.w,a1.x,a1.y,a1.z,a1.w};
      bf16x8 hi, lo;
#pragma unroll
      for (int i = 0; i < 8; ++i) { bf16 h, o; split2(av[i], h, o); hi[i] = h; lo[i] = o; }
      *(bf16x8*)&Ah[hf * 64 + srow][sk] = hi;
      *(bf16x8*)&Al[hf * 64 + srow][sk] = lo;
    }
#pragma unroll
    for (int s = 0; s < 3; ++s) {
      const float* wp = Ws_[s] + (size_t)(n0 + srow) * HID_ + kt * 32 + sk;
      const float4 w0 = *(const float4*)wp, w1 = *(const float4*)(wp + 4);
      const float wv[8] = {w0.x,w0.y,w0.z,w0.w,w1.x,w1.y,w1.z,w1.w};
      bf16x8 hi, lo;
#pragma unroll
      for (int i = 0; i < 8; ++i) { bf16 h, o; split2(wv[i], h, o); hi[i] = h; lo[i] = o; }
      *(bf16x8*)&Bh[s][srow][sk] = hi;
      *(bf16x8*)&Bl[s][srow][sk] = lo;
    }
    __syncthreads();
    bf16x8 fah[2], fal[2];
#pragma unroll
    for (int hf = 0; hf < 2; ++hf) {
      fah[hf] = *(const bf16x8*)&Ah[hf * 64 + w * 16 + cl][kg8];
      fal[hf] = *(const bf16x8*)&Al[hf * 64 + w * 16 + cl][kg8];
    }
#pragma unroll
    for (int s = 0; s < 3; ++s)
#pragma unroll
      for (int nf = 0; nf < 4; ++nf) {
        const bf16x8 fbh = *(const bf16x8*)&Bh[s][nf * 16 + cl][kg8];
        const bf16x8 fbl = *(const bf16x8*)&Bl[s][nf * 16 + cl][kg8];
#pragma unroll
        for (int hf = 0; hf < 2; ++hf) {
          acc[hf][s][nf] = mfma16(fah[hf], fbh, acc[hf][s][nf]);
          acc[hf][s][nf] = mfma16(fah[hf], fbl, acc[hf][s][nf]);
          acc[hf][s][nf] = mfma16(fal[hf], fbh, acc[hf][s][nf]);
        }
      }
    __syncthreads();
  }

  const float* bs_[3] = {bq, bk, bv};
#pragma unroll
  for (int s = 0; s < 3; ++s)
#pragma unroll
    for (int nf = 0; nf < 4; ++nf) {
      const int n = n0 + nf * 16 + cl;
      const float bias = bs_[s][n];
      const int hd = n >> 6, d = n & 63;
#pragma unroll
      for (int hf = 0; hf < 2; ++hf)
#pragma unroll
        for (int reg = 0; reg < 4; ++reg) {
          const int m = m0 + hf * 64 + w * 16 + g * 4 + reg;
          const int b = m >> 11, sq = m & (S_ - 1);
          const float val = acc[hf][s][nf][reg] + bias;
          if (s == 0) {
            bf16 h, o; split2(val * QSC_, h, o);
            const size_t idx = ((size_t)(b * H_ + hd) * S_ + sq) * D_ + d;
            Qh[idx] = h; Ql[idx] = o;
          } else if (s == 1) {
            Kb[((size_t)(b * H_ + hd) * S_ + sq) * D_ + d] = (bf16)val;
          } else {
            // tiled: [B,H, S/32, D, 32]
            Vt[(((size_t)(b * H_ + hd) * (S_ / 32) + (sq >> 5)) * D_ + d) * 32 + (sq & 31)]
                = (bf16)val;
          }
        }
    }
}

// ---------------- attention v6: no LDS K/V staging, no loop barriers,
// reg-pipelined K/V fragments, tiled V, XCD-aware wg swizzle.
// wave w: q-slice wq=(w&1)*16, j-half wh=w>>1. Lane: q=wq+cl, j per (nf,reg).
__global__ __launch_bounds__(256, 4) void attn_kernel(
    const bf16* __restrict__ Qh, const bf16* __restrict__ Ql,
    const bf16* __restrict__ Kb, const bf16* __restrict__ Vt,
    const float* __restrict__ msk2, const bf16* __restrict__ rkEb,
    const bf16* __restrict__ rvTb, float* __restrict__ out)
{
  // XCD swizzle: contiguous work chunks per XCD (2048 = 8 * 256)
  const int swz = (blockIdx.x & 7) * 256 + (blockIdx.x >> 3);
  const int qt = swz & 63, h = (swz >> 6) & 15, b = swz >> 10;
  const int q0 = qt * 32;
  const int tid = threadIdx.x;
  const int l = tid & 63, w = tid >> 6;
  const int wq = (w & 1) * 16, wh = w >> 1;
  const int cl = l & 15, g = l >> 4, kg8 = g * 8;
  const int lq = wq + cl;

  __shared__ __align__(16) bf16 T[32][296];
  __shared__ __align__(16) bf16 ph[32][72];
  __shared__ float ctxred[2][32][36];
  __shared__ float red[2][3][32];
  __shared__ float lsum_s[32];

  const size_t bh = (size_t)(b * H_ + h) * S_;

  bf16x8 qh0, qh1, ql0, ql1;
  {
    const size_t base = (bh + q0 + lq) * D_ + kg8;
    qh0 = *(const bf16x8*)(Qh + base);
    qh1 = *(const bf16x8*)(Qh + base + 32);
    ql0 = *(const bf16x8*)(Ql + base);
    ql1 = *(const bf16x8*)(Ql + base + 32);
  }

  // rel key scores into T
  {
    const int nt0 = wh ? 9 : 0, ntE = wh ? 17 : 9;
    for (int nt = nt0; nt < ntE; ++nt) {
      f32x4 r; r[0] = r[1] = r[2] = r[3] = 0.f;
      const bf16x8 a0 = *(const bf16x8*)(rkEb + (size_t)(nt * 16 + cl) * 64 + kg8);
      const bf16x8 a1 = *(const bf16x8*)(rkEb + (size_t)(nt * 16 + cl) * 64 + 32 + kg8);
      r = mfma16(a0, qh0, r); r = mfma16(a0, ql0, r);
      r = mfma16(a1, qh1, r); r = mfma16(a1, ql1, r);
      bf16x4 pk;
#pragma unroll
      for (int reg = 0; reg < 4; ++reg) pk[reg] = (bf16)r[reg];
      *(bf16x4*)&T[lq][nt * 16 + g * 4] = pk;
    }
  }
  __syncthreads();
  const float rs_lo = (float)T[lq][0];
  const float rs_hi = (float)T[lq][2 * R_];
  const int qg = q0 + lq;

  f32x4 ctx[4];
#pragma unroll
  for (int nf = 0; nf < 4; ++nf) { ctx[nf][0]=0.f; ctx[nf][1]=0.f; ctx[nf][2]=0.f; ctx[nf][3]=0.f; }
  float lsum = 0.f, plo = 0.f, phi = 0.f;

  const bf16* Kbase = Kb + bh * D_;
  const bf16* Vbase = Vt + bh * D_;            // per-(b,h) size S*D, tiled [S/32][D][32]
  const float* mbase = msk2 + b * S_;

  auto loadf = [&](int kt, bf16x8& a00, bf16x8& a01, bf16x8& a10, bf16x8& a11,
                   bf16x8& v0, bf16x8& v1, bf16x8& v2, bf16x8& v3) {
    const int j0 = kt * 64 + wh * 32;
    const bf16* kp = Kbase + (size_t)j0 * 64;
    a00 = *(const bf16x8*)(kp + cl * 64 + kg8);
    a01 = *(const bf16x8*)(kp + cl * 64 + 32 + kg8);
    a10 = *(const bf16x8*)(kp + (16 + cl) * 64 + kg8);
    a11 = *(const bf16x8*)(kp + (16 + cl) * 64 + 32 + kg8);
    const bf16* vp = Vbase + (size_t)(kt * 2 + wh) * (D_ * 32);
    v0 = *(const bf16x8*)(vp + (cl)      * 32 + kg8);
    v1 = *(const bf16x8*)(vp + (16 + cl) * 32 + kg8);
    v2 = *(const bf16x8*)(vp + (32 + cl) * 32 + kg8);
    v3 = *(const bf16x8*)(vp + (48 + cl) * 32 + kg8);
  };

  auto compute = [&](int kt, const bf16x8& a00, const bf16x8& a01,
                     const bf16x8& a10, const bf16x8& a11,
                     const bf16x8& v0, const bf16x8& v1,
                     const bf16x8& v2, const bf16x8& v3) {
    f32x4 s0, s1;
    s0[0]=s0[1]=s0[2]=s0[3]=0.f; s1[0]=s1[1]=s1[2]=s1[3]=0.f;
    s0 = mfma16(a00, qh0, s0); s0 = mfma16(a00, ql0, s0);
    s0 = mfma16(a01, qh1, s0); s0 = mfma16(a01, ql1, s0);
    s1 = mfma16(a10, qh0, s1); s1 = mfma16(a10, ql0, s1);
    s1 = mfma16(a11, qh1, s1); s1 = mfma16(a11, ql1, s1);

    const int j0 = kt * 64 + wh * 32;
    const float4 mk0 = *(const float4*)(mbase + j0 + g * 4);
    const float4 mk1 = *(const float4*)(mbase + j0 + 16 + g * 4);
    const int dlt = kt * 64 - q0;
    const int mode = (dlt <= -192) ? 0 : (dlt >= 192 ? 1 : 2);

#pragma unroll
    for (int nf = 0; nf < 2; ++nf) {
      const f32x4 sa = nf ? s1 : s0;
      const float4 mkv = nf ? mk1 : mk0;
      const float mks[4] = {mkv.x, mkv.y, mkv.z, mkv.w};
      float p[4];
      if (mode == 0) {
#pragma unroll
        for (int reg = 0; reg < 4; ++reg) p[reg] = exp2f(sa[reg] + rs_lo + mks[reg]);
        plo += (p[0] + p[1]) + (p[2] + p[3]);
      } else if (mode == 1) {
#pragma unroll
        for (int reg = 0; reg < 4; ++reg) p[reg] = exp2f(sa[reg] + rs_hi + mks[reg]);
        phi += (p[0] + p[1]) + (p[2] + p[3]);
      } else {
        const int jb = j0 + nf * 16 + g * 4;
#pragma unroll
        for (int reg = 0; reg < 4; ++reg) {
          const int bkv = jb + reg - qg + R_;
          const int bkc = bkv < 0 ? 0 : (bkv > 2 * R_ ? 2 * R_ : bkv);
          const float pv = exp2f(sa[reg] + (float)T[lq][bkc] + mks[reg]);
          p[reg] = pv;
          if (bkv <= 0)           plo += pv;
          else if (bkv >= 2 * R_) phi += pv;
          else                    T[lq][bkv] = (bf16)pv;   // unique owner cell
        }
      }
      lsum += (p[0] + p[1]) + (p[2] + p[3]);
      bf16x4 pk;
#pragma unroll
      for (int reg = 0; reg < 4; ++reg) pk[reg] = (bf16)p[reg];
      *(bf16x4*)&ph[lq][wh * 32 + nf * 16 + g * 4] = pk;
    }

    const bf16x8 pa = *(const bf16x8*)&ph[lq][wh * 32 + kg8];
    ctx[0] = mfma16(pa, v0, ctx[0]);
    ctx[1] = mfma16(pa, v1, ctx[1]);
    ctx[2] = mfma16(pa, v2, ctx[2]);
    ctx[3] = mfma16(pa, v3, ctx[3]);
  };

  // software pipeline, ping-pong register fragments, unroll-by-2
  bf16x8 A00,A01,A10,A11,AV0,AV1,AV2,AV3;
  bf16x8 B00,B01,B10,B11,BV0,BV1,BV2,BV3;
  loadf(0, A00,A01,A10,A11,AV0,AV1,AV2,AV3);
  for (int kt = 0; kt < S_ / 64; kt += 2) {
    loadf(kt + 1, B00,B01,B10,B11,BV0,BV1,BV2,BV3);
    compute(kt, A00,A01,A10,A11,AV0,AV1,AV2,AV3);
    if (kt + 2 < S_ / 64) loadf(kt + 2, A00,A01,A10,A11,AV0,AV1,AV2,AV3);
    compute(kt + 1, B00,B01,B10,B11,BV0,BV1,BV2,BV3);
  }

  // lane-group reductions (q fixed per lane)
  lsum += __shfl_xor(lsum, 16); lsum += __shfl_xor(lsum, 32);
  plo  += __shfl_xor(plo, 16);  plo  += __shfl_xor(plo, 32);
  phi  += __shfl_xor(phi, 16);  phi  += __shfl_xor(phi, 32);
  if (l < 16) {
    red[wh][0][wq + l] = lsum;
    red[wh][1][wq + l] = plo;
    red[wh][2][wq + l] = phi;
  }
  __syncthreads();   // all T interior writes + red complete

  // give away non-assigned ctx halves: wh=0 keeps nf{0,1}, wh=1 keeps nf{2,3}
  {
    const int nfs = wh ? 0 : 2;
#pragma unroll
    for (int k2 = 0; k2 < 2; ++k2)
#pragma unroll
      for (int reg = 0; reg < 4; ++reg)
        ctxred[wh][wq + g * 4 + reg][k2 * 16 + cl] = ctx[nfs + k2][reg];
  }
  if (tid < 32) {
    lsum_s[tid]    = red[0][0][tid] + red[1][0][tid];
    T[tid][0]      = (bf16)(red[0][1][tid] + red[1][1][tid]);
    T[tid][2 * R_] = (bf16)(red[0][2][tid] + red[1][2][tid]);
  }
  for (int t = tid; t < 32 * 32; t += 256) {
    const int c = t & 31;
    if (c) T[t >> 5][256 + c] = (bf16)0.f;
  }
  if (q0 < R_ || q0 > S_ - R_ - 32) {
    for (int t = tid; t < 32 * 256; t += 256) {
      const int r = t >> 8, c = t & 255;
      if (c >= 1) {
        const int j = q0 + r + c - R_;
        if (j < 0 || j >= S_) T[r][c] = (bf16)0.f;
      }
    }
  }
  __syncthreads();

  const int nfa = wh ? 2 : 0;
#pragma unroll
  for (int k2 = 0; k2 < 2; ++k2)
#pragma unroll
    for (int reg = 0; reg < 4; ++reg)
      ctx[nfa + k2][reg] += ctxred[wh ^ 1][wq + g * 4 + reg][k2 * 16 + cl];

  // rel-value GEMM: ctx += T(relp)[32][288] @ rvE
#pragma unroll
  for (int ks = 0; ks < 9; ++ks) {
    const bf16x8 pa = *(const bf16x8*)&T[lq][ks * 32 + kg8];
#pragma unroll
    for (int k2 = 0; k2 < 2; ++k2) {
      const int nf = nfa + k2;
      const bf16x8 vb = *(const bf16x8*)(rvTb + (size_t)(nf * 16 + cl) * 288 + ks * 32 + kg8);
      ctx[nf] = mfma16(pa, vb, ctx[nf]);
    }
  }

#pragma unroll
  for (int k2 = 0; k2 < 2; ++k2) {
    const int nf = nfa + k2;
#pragma unroll
    for (int reg = 0; reg < 4; ++reg) {
      const int qrow = wq + g * 4 + reg;
      const float invl = 1.f / lsum_s[qrow];
      out[(size_t)(b * S_ + q0 + qrow) * HID_ + h * 64 + nf * 16 + cl] = ctx[nf][reg] * invl;
    }
  }
}

extern "C" void kernel_launch(void* const* d_in, const int* in_sizes, int n_in,
                              void* d_out, int out_size, void* d_ws, size_t ws_size,
                              hipStream_t stream)
{
  (void)in_sizes; (void)n_in; (void)out_size; (void)ws_size;
  const float* hidden  = (const float*)d_in[0];
  const float* st_mask = (const float*)d_in[1];
  const float* Wq = (const float*)d_in[2];
  const float* bq = (const float*)d_in[3];
  const float* Wk = (const float*)d_in[4];
  const float* bk = (const float*)d_in[5];
  const float* Wv = (const float*)d_in[6];
  const float* bv = (const float*)d_in[7];
  const float* rkE = (const float*)d_in[8];
  const float* rvE = (const float*)d_in[9];
  float* out = (float*)d_out;

  const size_t per = (size_t)B_ * H_ * S_ * D_;   // 4,194,304 elements
  bf16* Qh   = (bf16*)d_ws;
  bf16* Ql   = Qh + per;
  bf16* Kb   = Ql + per;
  bf16* Vt   = Kb + per;
  bf16* rkEb = Vt + per;                 // 272*64
  bf16* rvTb = rkEb + 272 * 64;          // 64*288
  float* msk2 = (float*)(Qh + 4 * per + 36864);

  prep_kernel<<<dim3(40), 256, 0, stream>>>(st_mask, rkE, rvE, msk2, rkEb, rvTb);
  qkv_mfma_kernel<<<dim3(HID_ / 64, B_ * S_ / 128), 256, 0, stream>>>(
      hidden, Wq, bq, Wk, bk, Wv, bv, Qh, Ql, Kb, Vt);
  attn_kernel<<<dim3(2048), 256, 0, stream>>>(
      Qh, Ql, Kb, Vt, msk2, rkEb, rvTb, out);
}

// Round 7
// 377.082 us; speedup vs baseline: 1.2279x; 1.2279x over previous
//
#include <hip/hip_runtime.h>
#include <math.h>

typedef __bf16 bf16;
typedef __bf16 bf16x8 __attribute__((ext_vector_type(8)));
typedef __bf16 bf16x4 __attribute__((ext_vector_type(4)));
typedef float  f32x4  __attribute__((ext_vector_type(4)));

namespace {
constexpr int B_ = 2, S_ = 2048, HID_ = 1024, H_ = 16, D_ = 64, R_ = 128, NREL_ = 257;
constexpr float LOG2E_ = 1.44269504f;
constexpr float QSC_ = 0.125f * LOG2E_;   // 1/sqrt(D) and log2(e), folded into Q
}

static __device__ __forceinline__ f32x4 mfma16(bf16x8 a, bf16x8 b, f32x4 c) {
  return __builtin_amdgcn_mfma_f32_16x16x32_bf16(a, b, c, 0, 0, 0);
}
static __device__ __forceinline__ void split2(float f, bf16 &hi, bf16 &lo) {
  hi = (bf16)f; lo = (bf16)(f - (float)hi);
}

// ---------------- prep: scaled mask, rkE*8 -> bf16 [272][64], rvE^T -> bf16 [64][288]
__global__ void prep_kernel(const float* __restrict__ st_mask,
                            const float* __restrict__ rkE, const float* __restrict__ rvE,
                            float* __restrict__ msk2, bf16* __restrict__ rkEb,
                            bf16* __restrict__ rvTb)
{
  const int t0 = blockIdx.x * 256 + threadIdx.x;
  const int NT = gridDim.x * 256;
  for (int t = t0; t < B_ * S_; t += NT)
    msk2[t] = (1.f - st_mask[t]) * -10000.f * LOG2E_;
  for (int t = t0; t < 272 * 64; t += NT) {
    const int bk = t >> 6, d = t & 63;
    rkEb[t] = (bk < NREL_) ? (bf16)(rkE[bk * D_ + d] * 8.0f) : (bf16)0.f;
  }
  for (int t = t0; t < 64 * 288; t += NT) {
    const int d = t / 288, c = t - d * 288;
    rvTb[t] = (c < NREL_) ? (bf16)rvE[c * D_ + d] : (bf16)0.f;
  }
}

// ---------------- merged QKV projection, split-bf16 MFMA, 128x64 tile.
// V written TILED: [B,H, S/32, D, 32] so PV fragment loads are dense.
__global__ __launch_bounds__(256, 3) void qkv_mfma_kernel(
    const float* __restrict__ A,
    const float* __restrict__ Wq, const float* __restrict__ bq,
    const float* __restrict__ Wk, const float* __restrict__ bk,
    const float* __restrict__ Wv, const float* __restrict__ bv,
    bf16* __restrict__ Qh, bf16* __restrict__ Ql,
    bf16* __restrict__ Kb, bf16* __restrict__ Vt)
{
  const int n0 = blockIdx.x * 64;
  const int m0 = blockIdx.y * 128;
  const int tid = threadIdx.x;
  const int l = tid & 63, w = tid >> 6;
  const int cl = l & 15, g = l >> 4, kg8 = g * 8;

  __shared__ __align__(16) bf16 Ah[128][40], Al[128][40];
  __shared__ __align__(16) bf16 Bh[3][64][40], Bl[3][64][40];

  f32x4 acc[2][3][4];
#pragma unroll
  for (int hf = 0; hf < 2; ++hf)
#pragma unroll
    for (int s = 0; s < 3; ++s)
#pragma unroll
      for (int nf = 0; nf < 4; ++nf)
#pragma unroll
        for (int i = 0; i < 4; ++i) acc[hf][s][nf][i] = 0.f;

  const int srow = tid >> 2, sk = (tid & 3) * 8;
  const float* Ws_[3] = {Wq, Wk, Wv};

  for (int kt = 0; kt < HID_ / 32; ++kt) {
#pragma unroll
    for (int hf = 0; hf < 2; ++hf) {
      const float* ap = A + (size_t)(m0 + hf * 64 + srow) * HID_ + kt * 32 + sk;
      const float4 a0 = *(const float4*)ap, a1 = *(const float4*)(ap + 4);
      const float av[8] = {a0.x,a0.y,a0.z,a0.w,a1.x,a1.y,a1.z,a1.w};
      bf16x8 hi, lo;
#pragma unroll
      for (int i = 0; i < 8; ++i) { bf16 h, o; split2(av[i], h, o); hi[i] = h; lo[i] = o; }
      *(bf16x8*)&Ah[hf * 64 + srow][sk] = hi;
      *(bf16x8*)&Al[hf * 64 + srow][sk] = lo;
    }
#pragma unroll
    for (int s = 0; s < 3; ++s) {
      const float* wp = Ws_[s] + (size_t)(n0 + srow) * HID_ + kt * 32 + sk;
      const float4 w0 = *(const float4*)wp, w1 = *(const float4*)(wp + 4);
      const float wv[8] = {w0.x,w0.y,w0.z,w0.w,w1.x,w1.y,w1.z,w1.w};
      bf16x8 hi, lo;
#pragma unroll
      for (int i = 0; i < 8; ++i) { bf16 h, o; split2(wv[i], h, o); hi[i] = h; lo[i] = o; }
      *(bf16x8*)&Bh[s][srow][sk] = hi;
      *(bf16x8*)&Bl[s][srow][sk] = lo;
    }
    __syncthreads();
    bf16x8 fah[2], fal[2];
#pragma unroll
    for (int hf = 0; hf < 2; ++hf) {
      fah[hf] = *(const bf16x8*)&Ah[hf * 64 + w * 16 + cl][kg8];
      fal[hf] = *(const bf16x8*)&Al[hf * 64 + w * 16 + cl][kg8];
    }
#pragma unroll
    for (int s = 0; s < 3; ++s)
#pragma unroll
      for (int nf = 0; nf < 4; ++nf) {
        const bf16x8 fbh = *(const bf16x8*)&Bh[s][nf * 16 + cl][kg8];
        const bf16x8 fbl = *(const bf16x8*)&Bl[s][nf * 16 + cl][kg8];
#pragma unroll
        for (int hf = 0; hf < 2; ++hf) {
          acc[hf][s][nf] = mfma16(fah[hf], fbh, acc[hf][s][nf]);
          acc[hf][s][nf] = mfma16(fah[hf], fbl, acc[hf][s][nf]);
          acc[hf][s][nf] = mfma16(fal[hf], fbh, acc[hf][s][nf]);
        }
      }
    __syncthreads();
  }

  const float* bs_[3] = {bq, bk, bv};
#pragma unroll
  for (int s = 0; s < 3; ++s)
#pragma unroll
    for (int nf = 0; nf < 4; ++nf) {
      const int n = n0 + nf * 16 + cl;
      const float bias = bs_[s][n];
      const int hd = n >> 6, d = n & 63;
#pragma unroll
      for (int hf = 0; hf < 2; ++hf)
#pragma unroll
        for (int reg = 0; reg < 4; ++reg) {
          const int m = m0 + hf * 64 + w * 16 + g * 4 + reg;
          const int b = m >> 11, sq = m & (S_ - 1);
          const float val = acc[hf][s][nf][reg] + bias;
          if (s == 0) {
            bf16 h, o; split2(val * QSC_, h, o);
            const size_t idx = ((size_t)(b * H_ + hd) * S_ + sq) * D_ + d;
            Qh[idx] = h; Ql[idx] = o;
          } else if (s == 1) {
            Kb[((size_t)(b * H_ + hd) * S_ + sq) * D_ + d] = (bf16)val;
          } else {
            // tiled: [B,H, S/32, D, 32]
            Vt[(((size_t)(b * H_ + hd) * (S_ / 32) + (sq >> 5)) * D_ + d) * 32 + (sq & 31)]
                = (bf16)val;
          }
        }
    }
}

// ---------------- attention v7: barrier-free loop, macro-expanded register
// double-buffer (NO lambdas / reference params -> no scratch), tiled V,
// XCD-aware wg swizzle.
// wave w: q-slice wq=(w&1)*16, j-half wh=w>>1. Lane: q=wq+cl, j per (nf,reg).

#define LOADKV(kt, K0,K1,K2,K3,V0,V1,V2,V3) do {                               \
    const int j0_ = (kt) * 64 + wh * 32;                                       \
    const bf16* kp_ = Kbase + (size_t)j0_ * 64;                                \
    K0 = *(const bf16x8*)(kp_ + cl * 64 + kg8);                                \
    K1 = *(const bf16x8*)(kp_ + cl * 64 + 32 + kg8);                           \
    K2 = *(const bf16x8*)(kp_ + (16 + cl) * 64 + kg8);                         \
    K3 = *(const bf16x8*)(kp_ + (16 + cl) * 64 + 32 + kg8);                    \
    const bf16* vp_ = Vbase + (size_t)((kt) * 2 + wh) * (D_ * 32);             \
    V0 = *(const bf16x8*)(vp_ + cl * 32 + kg8);                                \
    V1 = *(const bf16x8*)(vp_ + (16 + cl) * 32 + kg8);                         \
    V2 = *(const bf16x8*)(vp_ + (32 + cl) * 32 + kg8);                         \
    V3 = *(const bf16x8*)(vp_ + (48 + cl) * 32 + kg8);                         \
  } while (0)

#define COMPUTE(kt, K0,K1,K2,K3,V0,V1,V2,V3) do {                              \
    f32x4 s0_, s1_;                                                            \
    s0_[0]=s0_[1]=s0_[2]=s0_[3]=0.f; s1_[0]=s1_[1]=s1_[2]=s1_[3]=0.f;          \
    s0_ = mfma16(K0, qh0, s0_); s0_ = mfma16(K0, ql0, s0_);                    \
    s0_ = mfma16(K1, qh1, s0_); s0_ = mfma16(K1, ql1, s0_);                    \
    s1_ = mfma16(K2, qh0, s1_); s1_ = mfma16(K2, ql0, s1_);                    \
    s1_ = mfma16(K3, qh1, s1_); s1_ = mfma16(K3, ql1, s1_);                    \
    const int j0_ = (kt) * 64 + wh * 32;                                       \
    const float4 mk0_ = *(const float4*)(mbase + j0_ + g * 4);                 \
    const float4 mk1_ = *(const float4*)(mbase + j0_ + 16 + g * 4);            \
    const int dlt_ = (kt) * 64 - q0;                                           \
    const int mode_ = (dlt_ <= -192) ? 0 : (dlt_ >= 192 ? 1 : 2);              \
    _Pragma("unroll")                                                          \
    for (int nf = 0; nf < 2; ++nf) {                                           \
      const f32x4 sa = nf ? s1_ : s0_;                                         \
      const float4 mkv = nf ? mk1_ : mk0_;                                     \
      const float mks[4] = {mkv.x, mkv.y, mkv.z, mkv.w};                       \
      float p_[4];                                                             \
      if (mode_ == 0) {                                                        \
        _Pragma("unroll")                                                      \
        for (int reg = 0; reg < 4; ++reg) p_[reg] = exp2f(sa[reg] + rs_lo + mks[reg]); \
        plo += (p_[0] + p_[1]) + (p_[2] + p_[3]);                              \
      } else if (mode_ == 1) {                                                 \
        _Pragma("unroll")                                                      \
        for (int reg = 0; reg < 4; ++reg) p_[reg] = exp2f(sa[reg] + rs_hi + mks[reg]); \
        phi += (p_[0] + p_[1]) + (p_[2] + p_[3]);                              \
      } else {                                                                 \
        const int jb_ = j0_ + nf * 16 + g * 4;                                 \
        _Pragma("unroll")                                                      \
        for (int reg = 0; reg < 4; ++reg) {                                    \
          const int bkv = jb_ + reg - qg + R_;                                 \
          const int bkc = bkv < 0 ? 0 : (bkv > 2 * R_ ? 2 * R_ : bkv);         \
          const float pv = exp2f(sa[reg] + (float)T[lq][bkc] + mks[reg]);      \
          p_[reg] = pv;                                                        \
          if (bkv <= 0)           plo += pv;                                   \
          else if (bkv >= 2 * R_) phi += pv;                                   \
          else                    T[lq][bkv] = (bf16)pv;                       \
        }                                                                      \
      }                                                                        \
      lsum += (p_[0] + p_[1]) + (p_[2] + p_[3]);                               \
      bf16x4 pk_;                                                              \
      _Pragma("unroll")                                                        \
      for (int reg = 0; reg < 4; ++reg) pk_[reg] = (bf16)p_[reg];              \
      *(bf16x4*)&ph[lq][wh * 32 + nf * 16 + g * 4] = pk_;                      \
    }                                                                          \
    const bf16x8 pa_ = *(const bf16x8*)&ph[lq][wh * 32 + kg8];                 \
    ctx[0] = mfma16(pa_, V0, ctx[0]);                                          \
    ctx[1] = mfma16(pa_, V1, ctx[1]);                                          \
    ctx[2] = mfma16(pa_, V2, ctx[2]);                                          \
    ctx[3] = mfma16(pa_, V3, ctx[3]);                                          \
  } while (0)

__global__ __launch_bounds__(256, 3) void attn_kernel(
    const bf16* __restrict__ Qh, const bf16* __restrict__ Ql,
    const bf16* __restrict__ Kb, const bf16* __restrict__ Vt,
    const float* __restrict__ msk2, const bf16* __restrict__ rkEb,
    const bf16* __restrict__ rvTb, float* __restrict__ out)
{
  // XCD swizzle: contiguous work chunks per XCD (2048 = 8 * 256)
  const int swz = (blockIdx.x & 7) * 256 + (blockIdx.x >> 3);
  const int qt = swz & 63, h = (swz >> 6) & 15, b = swz >> 10;
  const int q0 = qt * 32;
  const int tid = threadIdx.x;
  const int l = tid & 63, w = tid >> 6;
  const int wq = (w & 1) * 16, wh = w >> 1;
  const int cl = l & 15, g = l >> 4, kg8 = g * 8;
  const int lq = wq + cl;

  __shared__ __align__(16) bf16 T[32][296];
  __shared__ __align__(16) bf16 ph[32][72];
  __shared__ float ctxred[2][32][36];
  __shared__ float red[2][3][32];
  __shared__ float lsum_s[32];

  const size_t bh = (size_t)(b * H_ + h) * S_;

  bf16x8 qh0, qh1, ql0, ql1;
  {
    const size_t base = (bh + q0 + lq) * D_ + kg8;
    qh0 = *(const bf16x8*)(Qh + base);
    qh1 = *(const bf16x8*)(Qh + base + 32);
    ql0 = *(const bf16x8*)(Ql + base);
    ql1 = *(const bf16x8*)(Ql + base + 32);
  }

  // rel key scores into T
  {
    const int nt0 = wh ? 9 : 0, ntE = wh ? 17 : 9;
    for (int nt = nt0; nt < ntE; ++nt) {
      f32x4 r; r[0] = r[1] = r[2] = r[3] = 0.f;
      const bf16x8 a0 = *(const bf16x8*)(rkEb + (size_t)(nt * 16 + cl) * 64 + kg8);
      const bf16x8 a1 = *(const bf16x8*)(rkEb + (size_t)(nt * 16 + cl) * 64 + 32 + kg8);
      r = mfma16(a0, qh0, r); r = mfma16(a0, ql0, r);
      r = mfma16(a1, qh1, r); r = mfma16(a1, ql1, r);
      bf16x4 pk;
#pragma unroll
      for (int reg = 0; reg < 4; ++reg) pk[reg] = (bf16)r[reg];
      *(bf16x4*)&T[lq][nt * 16 + g * 4] = pk;
    }
  }
  __syncthreads();
  const float rs_lo = (float)T[lq][0];
  const float rs_hi = (float)T[lq][2 * R_];
  const int qg = q0 + lq;

  f32x4 ctx[4];
#pragma unroll
  for (int nf = 0; nf < 4; ++nf) { ctx[nf][0]=0.f; ctx[nf][1]=0.f; ctx[nf][2]=0.f; ctx[nf][3]=0.f; }
  float lsum = 0.f, plo = 0.f, phi = 0.f;

  const bf16* Kbase = Kb + bh * D_;
  const bf16* Vbase = Vt + bh * D_;            // per-(b,h) size S*D, tiled [S/32][D][32]
  const float* mbase = msk2 + b * S_;

  // explicit register double-buffer, manual 2x unroll
  bf16x8 aK0,aK1,aK2,aK3, aV0,aV1,aV2,aV3;
  bf16x8 bK0,bK1,bK2,bK3, bV0,bV1,bV2,bV3;
  LOADKV(0, aK0,aK1,aK2,aK3, aV0,aV1,aV2,aV3);
  for (int kt = 0; kt < S_ / 64; kt += 2) {
    LOADKV(kt + 1, bK0,bK1,bK2,bK3, bV0,bV1,bV2,bV3);
    COMPUTE(kt,    aK0,aK1,aK2,aK3, aV0,aV1,aV2,aV3);
    if (kt + 2 < S_ / 64)
      LOADKV(kt + 2, aK0,aK1,aK2,aK3, aV0,aV1,aV2,aV3);
    COMPUTE(kt + 1, bK0,bK1,bK2,bK3, bV0,bV1,bV2,bV3);
  }

  // lane-group reductions (q fixed per lane)
  lsum += __shfl_xor(lsum, 16); lsum += __shfl_xor(lsum, 32);
  plo  += __shfl_xor(plo, 16);  plo  += __shfl_xor(plo, 32);
  phi  += __shfl_xor(phi, 16);  phi  += __shfl_xor(phi, 32);
  if (l < 16) {
    red[wh][0][wq + l] = lsum;
    red[wh][1][wq + l] = plo;
    red[wh][2][wq + l] = phi;
  }
  __syncthreads();   // all T interior writes + red complete

  // give away non-assigned ctx halves: wh=0 keeps nf{0,1}, wh=1 keeps nf{2,3}
  {
    const int nfs = wh ? 0 : 2;
#pragma unroll
    for (int k2 = 0; k2 < 2; ++k2)
#pragma unroll
      for (int reg = 0; reg < 4; ++reg)
        ctxred[wh][wq + g * 4 + reg][k2 * 16 + cl] = ctx[nfs + k2][reg];
  }
  if (tid < 32) {
    lsum_s[tid]    = red[0][0][tid] + red[1][0][tid];
    T[tid][0]      = (bf16)(red[0][1][tid] + red[1][1][tid]);
    T[tid][2 * R_] = (bf16)(red[0][2][tid] + red[1][2][tid]);
  }
  for (int t = tid; t < 32 * 32; t += 256) {
    const int c = t & 31;
    if (c) T[t >> 5][256 + c] = (bf16)0.f;
  }
  if (q0 < R_ || q0 > S_ - R_ - 32) {
    for (int t = tid; t < 32 * 256; t += 256) {
      const int r = t >> 8, c = t & 255;
      if (c >= 1) {
        const int j = q0 + r + c - R_;
        if (j < 0 || j >= S_) T[r][c] = (bf16)0.f;
      }
    }
  }
  __syncthreads();

  const int nfa = wh ? 2 : 0;
#pragma unroll
  for (int k2 = 0; k2 < 2; ++k2)
#pragma unroll
    for (int reg = 0; reg < 4; ++reg)
      ctx[nfa + k2][reg] += ctxred[wh ^ 1][wq + g * 4 + reg][k2 * 16 + cl];

  // rel-value GEMM: ctx += T(relp)[32][288] @ rvE
#pragma unroll
  for (int ks = 0; ks < 9; ++ks) {
    const bf16x8 pa = *(const bf16x8*)&T[lq][ks * 32 + kg8];
#pragma unroll
    for (int k2 = 0; k2 < 2; ++k2) {
      const int nf = nfa + k2;
      const bf16x8 vb = *(const bf16x8*)(rvTb + (size_t)(nf * 16 + cl) * 288 + ks * 32 + kg8);
      ctx[nf] = mfma16(pa, vb, ctx[nf]);
    }
  }

#pragma unroll
  for (int k2 = 0; k2 < 2; ++k2) {
    const int nf = nfa + k2;
#pragma unroll
    for (int reg = 0; reg < 4; ++reg) {
      const int qrow = wq + g * 4 + reg;
      const float invl = 1.f / lsum_s[qrow];
      out[(size_t)(b * S_ + q0 + qrow) * HID_ + h * 64 + nf * 16 + cl] = ctx[nf][reg] * invl;
    }
  }
}

extern "C" void kernel_launch(void* const* d_in, const int* in_sizes, int n_in,
                              void* d_out, int out_size, void* d_ws, size_t ws_size,
                              hipStream_t stream)
{
  (void)in_sizes; (void)n_in; (void)out_size; (void)ws_size;
  const float* hidden  = (const float*)d_in[0];
  const float* st_mask = (const float*)d_in[1];
  const float* Wq = (const float*)d_in[2];
  const float* bq = (const float*)d_in[3];
  const float* Wk = (const float*)d_in[4];
  const float* bk = (const float*)d_in[5];
  const float* Wv = (const float*)d_in[6];
  const float* bv = (const float*)d_in[7];
  const float* rkE = (const float*)d_in[8];
  const float* rvE = (const float*)d_in[9];
  float* out = (float*)d_out;

  const size_t per = (size_t)B_ * H_ * S_ * D_;   // 4,194,304 elements
  bf16* Qh   = (bf16*)d_ws;
  bf16* Ql   = Qh + per;
  bf16* Kb   = Ql + per;
  bf16* Vt   = Kb + per;
  bf16* rkEb = Vt + per;                 // 272*64
  bf16* rvTb = rkEb + 272 * 64;          // 64*288
  float* msk2 = (float*)(Qh + 4 * per + 36864);

  prep_kernel<<<dim3(40), 256, 0, stream>>>(st_mask, rkE, rvE, msk2, rkEb, rvTb);
  qkv_mfma_kernel<<<dim3(HID_ / 64, B_ * S_ / 128), 256, 0, stream>>>(
      hidden, Wq, bq, Wk, bk, Wv, bv, Qh, Ql, Kb, Vt);
  attn_kernel<<<dim3(2048), 256, 0, stream>>>(
      Qh, Ql, Kb, Vt, msk2, rkEb, rvTb, out);
}

// Round 8
// 237.313 us; speedup vs baseline: 1.9511x; 1.5890x over previous
//
#include <hip/hip_runtime.h>
#include <math.h>

typedef __bf16 bf16;
typedef __bf16 bf16x8 __attribute__((ext_vector_type(8)));
typedef __bf16 bf16x4 __attribute__((ext_vector_type(4)));
typedef float  f32x4  __attribute__((ext_vector_type(4)));

namespace {
constexpr int B_ = 2, S_ = 2048, HID_ = 1024, H_ = 16, D_ = 64, R_ = 128, NREL_ = 257;
constexpr float LOG2E_ = 1.44269504f;
constexpr float QSC_ = 0.125f * LOG2E_;   // 1/sqrt(D) and log2(e), folded into Q
}

static __device__ __forceinline__ f32x4 mfma16(bf16x8 a, bf16x8 b, f32x4 c) {
  return __builtin_amdgcn_mfma_f32_16x16x32_bf16(a, b, c, 0, 0, 0);
}
static __device__ __forceinline__ void split2(float f, bf16 &hi, bf16 &lo) {
  hi = (bf16)f; lo = (bf16)(f - (float)hi);
}
// async global->LDS, 16B per lane. dst must be wave-uniform base (+lane*16 by HW).
static __device__ __forceinline__ void gload16(const bf16* g, bf16* l) {
  __builtin_amdgcn_global_load_lds(
      (const __attribute__((address_space(1))) void*)g,
      (__attribute__((address_space(3))) void*)l, 16, 0, 0);
}

// ---------------- prep: scaled mask, rkE*8 -> bf16 [272][64], rvE^T -> bf16 [64][288]
__global__ void prep_kernel(const float* __restrict__ st_mask,
                            const float* __restrict__ rkE, const float* __restrict__ rvE,
                            float* __restrict__ msk2, bf16* __restrict__ rkEb,
                            bf16* __restrict__ rvTb)
{
  const int t0 = blockIdx.x * 256 + threadIdx.x;
  const int NT = gridDim.x * 256;
  for (int t = t0; t < B_ * S_; t += NT)
    msk2[t] = (1.f - st_mask[t]) * -10000.f * LOG2E_;
  for (int t = t0; t < 272 * 64; t += NT) {
    const int bk = t >> 6, d = t & 63;
    rkEb[t] = (bk < NREL_) ? (bf16)(rkE[bk * D_ + d] * 8.0f) : (bf16)0.f;
  }
  for (int t = t0; t < 64 * 288; t += NT) {
    const int d = t / 288, c = t - d * 288;
    rvTb[t] = (c < NREL_) ? (bf16)rvE[c * D_ + d] : (bf16)0.f;
  }
}

// ---------------- merged QKV projection, split-bf16 MFMA, 128x64 tile.
// V written TILED: [B,H, S/32, D, 32] so PV staging is dense.
__global__ __launch_bounds__(256, 3) void qkv_mfma_kernel(
    const float* __restrict__ A,
    const float* __restrict__ Wq, const float* __restrict__ bq,
    const float* __restrict__ Wk, const float* __restrict__ bk,
    const float* __restrict__ Wv, const float* __restrict__ bv,
    bf16* __restrict__ Qh, bf16* __restrict__ Ql,
    bf16* __restrict__ Kb, bf16* __restrict__ Vt)
{
  const int n0 = blockIdx.x * 64;
  const int m0 = blockIdx.y * 128;
  const int tid = threadIdx.x;
  const int l = tid & 63, w = tid >> 6;
  const int cl = l & 15, g = l >> 4, kg8 = g * 8;

  __shared__ __align__(16) bf16 Ah[128][40], Al[128][40];
  __shared__ __align__(16) bf16 Bh[3][64][40], Bl[3][64][40];

  f32x4 acc[2][3][4];
#pragma unroll
  for (int hf = 0; hf < 2; ++hf)
#pragma unroll
    for (int s = 0; s < 3; ++s)
#pragma unroll
      for (int nf = 0; nf < 4; ++nf)
#pragma unroll
        for (int i = 0; i < 4; ++i) acc[hf][s][nf][i] = 0.f;

  const int srow = tid >> 2, sk = (tid & 3) * 8;
  const float* Ws_[3] = {Wq, Wk, Wv};

  for (int kt = 0; kt < HID_ / 32; ++kt) {
#pragma unroll
    for (int hf = 0; hf < 2; ++hf) {
      const float* ap = A + (size_t)(m0 + hf * 64 + srow) * HID_ + kt * 32 + sk;
      const float4 a0 = *(const float4*)ap, a1 = *(const float4*)(ap + 4);
      const float av[8] = {a0.x,a0.y,a0.z,a0.w,a1.x,a1.y,a1.z,a1.w};
      bf16x8 hi, lo;
#pragma unroll
      for (int i = 0; i < 8; ++i) { bf16 h, o; split2(av[i], h, o); hi[i] = h; lo[i] = o; }
      *(bf16x8*)&Ah[hf * 64 + srow][sk] = hi;
      *(bf16x8*)&Al[hf * 64 + srow][sk] = lo;
    }
#pragma unroll
    for (int s = 0; s < 3; ++s) {
      const float* wp = Ws_[s] + (size_t)(n0 + srow) * HID_ + kt * 32 + sk;
      const float4 w0 = *(const float4*)wp, w1 = *(const float4*)(wp + 4);
      const float wv[8] = {w0.x,w0.y,w0.z,w0.w,w1.x,w1.y,w1.z,w1.w};
      bf16x8 hi, lo;
#pragma unroll
      for (int i = 0; i < 8; ++i) { bf16 h, o; split2(wv[i], h, o); hi[i] = h; lo[i] = o; }
      *(bf16x8*)&Bh[s][srow][sk] = hi;
      *(bf16x8*)&Bl[s][srow][sk] = lo;
    }
    __syncthreads();
    bf16x8 fah[2], fal[2];
#pragma unroll
    for (int hf = 0; hf < 2; ++hf) {
      fah[hf] = *(const bf16x8*)&Ah[hf * 64 + w * 16 + cl][kg8];
      fal[hf] = *(const bf16x8*)&Al[hf * 64 + w * 16 + cl][kg8];
    }
#pragma unroll
    for (int s = 0; s < 3; ++s)
#pragma unroll
      for (int nf = 0; nf < 4; ++nf) {
        const bf16x8 fbh = *(const bf16x8*)&Bh[s][nf * 16 + cl][kg8];
        const bf16x8 fbl = *(const bf16x8*)&Bl[s][nf * 16 + cl][kg8];
#pragma unroll
        for (int hf = 0; hf < 2; ++hf) {
          acc[hf][s][nf] = mfma16(fah[hf], fbh, acc[hf][s][nf]);
          acc[hf][s][nf] = mfma16(fah[hf], fbl, acc[hf][s][nf]);
          acc[hf][s][nf] = mfma16(fal[hf], fbh, acc[hf][s][nf]);
        }
      }
    __syncthreads();
  }

  const float* bs_[3] = {bq, bk, bv};
#pragma unroll
  for (int s = 0; s < 3; ++s)
#pragma unroll
    for (int nf = 0; nf < 4; ++nf) {
      const int n = n0 + nf * 16 + cl;
      const float bias = bs_[s][n];
      const int hd = n >> 6, d = n & 63;
#pragma unroll
      for (int hf = 0; hf < 2; ++hf)
#pragma unroll
        for (int reg = 0; reg < 4; ++reg) {
          const int m = m0 + hf * 64 + w * 16 + g * 4 + reg;
          const int b = m >> 11, sq = m & (S_ - 1);
          const float val = acc[hf][s][nf][reg] + bias;
          if (s == 0) {
            bf16 h, o; split2(val * QSC_, h, o);
            const size_t idx = ((size_t)(b * H_ + hd) * S_ + sq) * D_ + d;
            Qh[idx] = h; Ql[idx] = o;
          } else if (s == 1) {
            Kb[((size_t)(b * H_ + hd) * S_ + sq) * D_ + d] = (bf16)val;
          } else {
            Vt[(((size_t)(b * H_ + hd) * (S_ / 32) + (sq >> 5)) * D_ + d) * 32 + (sq & 31)]
                = (bf16)val;
          }
        }
    }
}

// ---------------- attention v8: 8 waves / 64 q-rows, LDS K/V double-buffer
// staged via global_load_lds (16B), XOR-swizzled (linear dest + inv-swz source
// + swz read), 2 barriers/kt, swapped QK^T, shared rs/relp T-table.
// wave w: q-slice wq=(w&3)*16, j/d-half wh=w>>2. Lane: q=wq+cl, j per (nf,reg).
__global__ __launch_bounds__(512, 4) void attn_kernel(
    const bf16* __restrict__ Qh, const bf16* __restrict__ Ql,
    const bf16* __restrict__ Kb, const bf16* __restrict__ Vt,
    const float* __restrict__ msk2, const bf16* __restrict__ rkEb,
    const bf16* __restrict__ rvTb, float* __restrict__ out)
{
  // XCD swizzle over 1024 wgs = 8 XCDs x 128
  const int swz = ((int)blockIdx.x & 7) * 128 + ((int)blockIdx.x >> 3);
  const int qt = swz & 31, h = (swz >> 5) & 15, b = swz >> 9;
  const int q0 = qt * 64;
  const int tid = threadIdx.x;
  const int l = tid & 63, w = tid >> 6;
  const int wq = (w & 3) * 16;    // q-slice
  const int wh = w >> 2;          // j-half (QK^T) and d-half (PV)
  const int cl = l & 15, g = l >> 4, kg8 = g * 8;
  const int lq = wq + cl;

  __shared__ __align__(16) bf16 k_s[2][4096];   // [64 j][64 k] linear, swz chunks
  __shared__ __align__(16) bf16 v_s[2][4096];   // 2 subtiles [64 d][32 j], swz
  __shared__ __align__(16) bf16 T[64][288];     // rs then relp
  __shared__ __align__(16) bf16 ph[64][72];     // P roundtrip
  __shared__ float red[2][3][64];
  __shared__ float lsum_s[64];

  const size_t bh = (size_t)(b * H_ + h) * S_;
  const bf16* Kbase = Kb + bh * D_;             // [S][64]
  const bf16* Vbase = Vt + bh * D_;             // tiled [S/32][64][32]
  const float* mbase = msk2 + b * S_;

  // per-thread staging source offsets (inverse-swizzled)
  const int tKr = tid >> 3;
  const int koff = tKr * 64 + (((tid & 7) ^ (tKr & 7)) << 3);
  const int tVs = tid >> 8, tVu = tid & 255, tVd = tVu >> 2;
  const int voff = tVs * 2048 + tVd * 32 + ((((tVu & 3) ^ (tVd & 3))) << 3);
  bf16* kdst0 = &k_s[0][w * 512]; bf16* kdst1 = &k_s[1][w * 512];
  bf16* vdst0 = &v_s[0][w * 512]; bf16* vdst1 = &v_s[1][w * 512];

  // stage kt=0 (flies under the rs prologue)
  gload16(Kbase + koff, kdst0);
  gload16(Vbase + voff, vdst0);

  // Q fragments (pre-scaled by log2e/8)
  bf16x8 qh0, qh1, ql0, ql1;
  {
    const size_t base = (bh + q0 + lq) * D_ + kg8;
    qh0 = *(const bf16x8*)(Qh + base);
    qh1 = *(const bf16x8*)(Qh + base + 32);
    ql0 = *(const bf16x8*)(Ql + base);
    ql1 = *(const bf16x8*)(Ql + base + 32);
  }

  // rel key scores into T: wave (wq,wh) does nt range for its q-slice
  {
    const int nt0 = wh ? 9 : 0, ntE = wh ? 17 : 9;
    for (int nt = nt0; nt < ntE; ++nt) {
      f32x4 r; r[0] = r[1] = r[2] = r[3] = 0.f;
      const bf16x8 a0 = *(const bf16x8*)(rkEb + (size_t)(nt * 16 + cl) * 64 + kg8);
      const bf16x8 a1 = *(const bf16x8*)(rkEb + (size_t)(nt * 16 + cl) * 64 + 32 + kg8);
      r = mfma16(a0, qh0, r); r = mfma16(a0, ql0, r);
      r = mfma16(a1, qh1, r); r = mfma16(a1, ql1, r);
      bf16x4 pk;
#pragma unroll
      for (int reg = 0; reg < 4; ++reg) pk[reg] = (bf16)r[reg];
      *(bf16x4*)&T[lq][nt * 16 + g * 4] = pk;
    }
  }
  __syncthreads();   // T ready; kt=0 stage drained (vmcnt0 in syncthreads)

  const float rs_lo = (float)T[lq][0];
  const float rs_hi = (float)T[lq][2 * R_];
  const int qg = q0 + lq;

  f32x4 ctx0, ctx1;
#pragma unroll
  for (int i = 0; i < 4; ++i) { ctx0[i] = 0.f; ctx1[i] = 0.f; }
  float lsum = 0.f, plo = 0.f, phi = 0.f;

  const int r00 = wh * 32 + cl, r10 = wh * 32 + 16 + cl;
  const int ksw = (r00 & 7);                    // same for r10
  const int rd0 = wh * 32 + cl, rd1 = wh * 32 + 16 + cl;
  const int vsw = (rd0 & 3);                    // same for rd1
  const int e00 = r00 * 64 + 8 * (g ^ ksw),  e01 = r00 * 64 + 8 * ((4 + g) ^ ksw);
  const int e10 = r10 * 64 + 8 * (g ^ ksw),  e11 = r10 * 64 + 8 * ((4 + g) ^ ksw);
  const int f0 = rd0 * 32 + 8 * (g ^ vsw),   f1 = rd1 * 32 + 8 * (g ^ vsw);

  int cur = 0;
  for (int kt = 0; kt < S_ / 64; ++kt) {
    // issue next-tile stage first (in flight across phases)
    if (kt + 1 < S_ / 64) {
      gload16(Kbase + (size_t)(kt + 1) * 4096 + koff, cur ? kdst0 : kdst1);
      gload16(Vbase + (size_t)(kt + 1) * 4096 + voff, cur ? vdst0 : vdst1);
    }

    // K fragments (swizzled ds_read_b128)
    const bf16* kc = &k_s[cur][0];
    const bf16x8 a00 = *(const bf16x8*)&kc[e00];
    const bf16x8 a01 = *(const bf16x8*)&kc[e01];
    const bf16x8 a10 = *(const bf16x8*)&kc[e10];
    const bf16x8 a11 = *(const bf16x8*)&kc[e11];

    f32x4 s0, s1;
    s0[0]=s0[1]=s0[2]=s0[3]=0.f; s1[0]=s1[1]=s1[2]=s1[3]=0.f;
    s0 = mfma16(a00, qh0, s0); s0 = mfma16(a00, ql0, s0);
    s0 = mfma16(a01, qh1, s0); s0 = mfma16(a01, ql1, s0);
    s1 = mfma16(a10, qh0, s1); s1 = mfma16(a10, ql0, s1);
    s1 = mfma16(a11, qh1, s1); s1 = mfma16(a11, ql1, s1);

    const int j0 = kt * 64 + wh * 32;
    const float4 mk0 = *(const float4*)(mbase + j0 + g * 4);
    const float4 mk1 = *(const float4*)(mbase + j0 + 16 + g * 4);
    const int dlt = kt * 64 - q0;
    const int mode = (dlt <= -192) ? 0 : (dlt >= 192 ? 1 : 2);

#pragma unroll
    for (int nf = 0; nf < 2; ++nf) {
      const f32x4 sa = nf ? s1 : s0;
      const float4 mkv = nf ? mk1 : mk0;
      const float mks[4] = {mkv.x, mkv.y, mkv.z, mkv.w};
      float p[4];
      if (mode == 0) {
#pragma unroll
        for (int reg = 0; reg < 4; ++reg) p[reg] = exp2f(sa[reg] + rs_lo + mks[reg]);
        plo += (p[0] + p[1]) + (p[2] + p[3]);
      } else if (mode == 1) {
#pragma unroll
        for (int reg = 0; reg < 4; ++reg) p[reg] = exp2f(sa[reg] + rs_hi + mks[reg]);
        phi += (p[0] + p[1]) + (p[2] + p[3]);
      } else {
        const int jb = j0 + nf * 16 + g * 4;
#pragma unroll
        for (int reg = 0; reg < 4; ++reg) {
          const int bkv = jb + reg - qg + R_;
          const int bkc = bkv < 0 ? 0 : (bkv > 2 * R_ ? 2 * R_ : bkv);
          const float pv = exp2f(sa[reg] + (float)T[lq][bkc] + mks[reg]);
          p[reg] = pv;
          if (bkv <= 0)           plo += pv;
          else if (bkv >= 2 * R_) phi += pv;
          else                    T[lq][bkv] = (bf16)pv;   // unique owner cell
        }
      }
      lsum += (p[0] + p[1]) + (p[2] + p[3]);
      bf16x4 pk;
#pragma unroll
      for (int reg = 0; reg < 4; ++reg) pk[reg] = (bf16)p[reg];
      *(bf16x4*)&ph[lq][wh * 32 + nf * 16 + g * 4] = pk;
    }
    __syncthreads();   // barrier1: all P written (+ next stage drained)

    // PV: P over BOTH j-halves x own d-half
    const bf16x8 pa0 = *(const bf16x8*)&ph[lq][kg8];
    const bf16x8 pa1 = *(const bf16x8*)&ph[lq][32 + kg8];
    const bf16* vc = &v_s[cur][0];
    const bf16x8 vb00 = *(const bf16x8*)&vc[f0];
    const bf16x8 vb01 = *(const bf16x8*)&vc[2048 + f0];
    const bf16x8 vb10 = *(const bf16x8*)&vc[f1];
    const bf16x8 vb11 = *(const bf16x8*)&vc[2048 + f1];
    ctx0 = mfma16(pa0, vb00, ctx0); ctx0 = mfma16(pa1, vb01, ctx0);
    ctx1 = mfma16(pa0, vb10, ctx1); ctx1 = mfma16(pa1, vb11, ctx1);
    __syncthreads();   // barrier2: cur buffer free for restage
    cur ^= 1;
  }

  // lane-group reductions (q fixed per lane)
  lsum += __shfl_xor(lsum, 16); lsum += __shfl_xor(lsum, 32);
  plo  += __shfl_xor(plo, 16);  plo  += __shfl_xor(plo, 32);
  phi  += __shfl_xor(phi, 16);  phi  += __shfl_xor(phi, 32);
  if (l < 16) {
    red[wh][0][wq + l] = lsum;
    red[wh][1][wq + l] = plo;
    red[wh][2][wq + l] = phi;
  }
  __syncthreads();
  if (tid < 64) {
    lsum_s[tid]    = red[0][0][tid] + red[1][0][tid];
    T[tid][0]      = (bf16)(red[0][1][tid] + red[1][1][tid]);
    T[tid][2 * R_] = (bf16)(red[0][2][tid] + red[1][2][tid]);
  }
  // zero pad cols 257..287
  for (int t = tid; t < 64 * 32; t += 512) {
    const int c = t & 31;
    if (c) T[t >> 5][256 + c] = (bf16)0.f;
  }
  // zero interior cells whose j is out of range (edge q-tiles only)
  if (q0 < R_ || q0 > S_ - R_ - 64) {
    for (int t = tid; t < 64 * 256; t += 512) {
      const int r = t >> 8, c = t & 255;
      if (c >= 1) {
        const int j = q0 + r + c - R_;
        if (j < 0 || j >= S_) T[r][c] = (bf16)0.f;
      }
    }
  }
  __syncthreads();

  // rel-value GEMM: ctx += T(relp)[64][288] @ rvE  (rvTb rows = d)
#pragma unroll
  for (int ks = 0; ks < 9; ++ks) {
    const bf16x8 pa = *(const bf16x8*)&T[lq][ks * 32 + kg8];
    const bf16x8 v0 = *(const bf16x8*)(rvTb + (size_t)(wh * 32 + cl) * 288 + ks * 32 + kg8);
    const bf16x8 v1 = *(const bf16x8*)(rvTb + (size_t)(wh * 32 + 16 + cl) * 288 + ks * 32 + kg8);
    ctx0 = mfma16(pa, v0, ctx0);
    ctx1 = mfma16(pa, v1, ctx1);
  }

  // normalize + store out[b][q][h*64 + wh*32 + {0,16} + cl]
#pragma unroll
  for (int reg = 0; reg < 4; ++reg) {
    const int qrow = wq + g * 4 + reg;
    const float invl = 1.f / lsum_s[qrow];
    float* op = out + (size_t)(b * S_ + q0 + qrow) * HID_ + h * 64 + wh * 32;
    op[cl]      = ctx0[reg] * invl;
    op[16 + cl] = ctx1[reg] * invl;
  }
}

extern "C" void kernel_launch(void* const* d_in, const int* in_sizes, int n_in,
                              void* d_out, int out_size, void* d_ws, size_t ws_size,
                              hipStream_t stream)
{
  (void)in_sizes; (void)n_in; (void)out_size; (void)ws_size;
  const float* hidden  = (const float*)d_in[0];
  const float* st_mask = (const float*)d_in[1];
  const float* Wq = (const float*)d_in[2];
  const float* bq = (const float*)d_in[3];
  const float* Wk = (const float*)d_in[4];
  const float* bk = (const float*)d_in[5];
  const float* Wv = (const float*)d_in[6];
  const float* bv = (const float*)d_in[7];
  const float* rkE = (const float*)d_in[8];
  const float* rvE = (const float*)d_in[9];
  float* out = (float*)d_out;

  const size_t per = (size_t)B_ * H_ * S_ * D_;   // 4,194,304 elements
  bf16* Qh   = (bf16*)d_ws;
  bf16* Ql   = Qh + per;
  bf16* Kb   = Ql + per;
  bf16* Vt   = Kb + per;
  bf16* rkEb = Vt + per;                 // 272*64
  bf16* rvTb = rkEb + 272 * 64;          // 64*288
  float* msk2 = (float*)(Qh + 4 * per + 36864);

  prep_kernel<<<dim3(40), 256, 0, stream>>>(st_mask, rkE, rvE, msk2, rkEb, rvTb);
  qkv_mfma_kernel<<<dim3(HID_ / 64, B_ * S_ / 128), 256, 0, stream>>>(
      hidden, Wq, bq, Wk, bk, Wv, bv, Qh, Ql, Kb, Vt);
  attn_kernel<<<dim3(1024), 512, 0, stream>>>(
      Qh, Ql, Kb, Vt, msk2, rkEb, rvTb, out);
}

// Round 10
// 189.804 us; speedup vs baseline: 2.4395x; 1.2503x over previous
//
#include <hip/hip_runtime.h>
#include <math.h>

typedef __bf16 bf16;
typedef __bf16 bf16x8 __attribute__((ext_vector_type(8)));
typedef __bf16 bf16x4 __attribute__((ext_vector_type(4)));
typedef float  f32x4  __attribute__((ext_vector_type(4)));

namespace {
constexpr int B_ = 2, S_ = 2048, HID_ = 1024, H_ = 16, D_ = 64, R_ = 128, NREL_ = 257;
constexpr float LOG2E_ = 1.44269504f;
constexpr float QSC_ = 0.125f * LOG2E_;   // 1/sqrt(D) and log2(e), folded into Q
}

static __device__ __forceinline__ f32x4 mfma16(bf16x8 a, bf16x8 b, f32x4 c) {
  return __builtin_amdgcn_mfma_f32_16x16x32_bf16(a, b, c, 0, 0, 0);
}
static __device__ __forceinline__ void split2(float f, bf16 &hi, bf16 &lo) {
  hi = (bf16)f; lo = (bf16)(f - (float)hi);
}
// async global->LDS, 16B per lane. dst must be wave-uniform base (+lane*16 by HW).
static __device__ __forceinline__ void gload16(const bf16* g, bf16* l) {
  __builtin_amdgcn_global_load_lds(
      (const __attribute__((address_space(1))) void*)g,
      (__attribute__((address_space(3))) void*)l, 16, 0, 0);
}

// ---------------- prep: mask, rkE*8, rvE^T, hidden split (Ah/Al), W -> bf16
__global__ __launch_bounds__(256) void prep_kernel(
    const float* __restrict__ st_mask, const float* __restrict__ rkE,
    const float* __restrict__ rvE, const float* __restrict__ hidden,
    const float* __restrict__ Wq, const float* __restrict__ Wk,
    const float* __restrict__ Wv,
    float* __restrict__ msk2, bf16* __restrict__ rkEb, bf16* __restrict__ rvTb,
    bf16* __restrict__ Ahg, bf16* __restrict__ Alg, bf16* __restrict__ Wbg)
{
  const int t0 = blockIdx.x * 256 + threadIdx.x;
  const int NT = gridDim.x * 256;
  for (int t = t0; t < B_ * S_; t += NT)
    msk2[t] = (1.f - st_mask[t]) * -10000.f * LOG2E_;
  for (int t = t0; t < 272 * 64; t += NT) {
    const int bk = t >> 6, d = t & 63;
    rkEb[t] = (bk < NREL_) ? (bf16)(rkE[bk * D_ + d] * 8.0f) : (bf16)0.f;
  }
  for (int t = t0; t < 64 * 288; t += NT) {
    const int d = t / 288, c = t - d * 288;
    rvTb[t] = (c < NREL_) ? (bf16)rvE[c * D_ + d] : (bf16)0.f;
  }
  // hidden split: 4096*1024 f32 -> Ah/Al bf16
  for (int t = t0; t < (B_ * S_ * HID_) / 4; t += NT) {
    const float4 a = ((const float4*)hidden)[t];
    const float av[4] = {a.x, a.y, a.z, a.w};
    bf16x4 h, o;
#pragma unroll
    for (int i = 0; i < 4; ++i) {
      bf16 th, tl;
      split2(av[i], th, tl);
      h[i] = th; o[i] = tl;
    }
    *(bf16x4*)&Ahg[t * 4] = h;
    *(bf16x4*)&Alg[t * 4] = o;
  }
  // W -> bf16 (single), [3][1024][1024]
  for (int t = t0; t < 3 * (HID_ * HID_) / 4; t += NT) {
    const int s = t >> 18, i = t & 262143;
    const float4 wv4 = ((const float4*)(s == 0 ? Wq : s == 1 ? Wk : Wv))[i];
    bf16x4 h;
    h[0] = (bf16)wv4.x; h[1] = (bf16)wv4.y; h[2] = (bf16)wv4.z; h[3] = (bf16)wv4.w;
    *(bf16x4*)&Wbg[s * 1048576 + i * 4] = h;
  }
}

// ---------------- qkv GEMM v9: pure bf16, gload_lds double-buffered 2-phase,
// A split (hi/lo) x W single = 2 MFMA/output. 128-row x 64-col-per-s tile.
// wave w: m-rows {hf*64 + w*16 .. +15}. 1 barrier/kt.
__global__ __launch_bounds__(256, 2) void qkv_mfma_kernel(
    const bf16* __restrict__ Ahg, const bf16* __restrict__ Alg,
    const bf16* __restrict__ Wbg,
    const float* __restrict__ bq, const float* __restrict__ bk,
    const float* __restrict__ bv,
    bf16* __restrict__ Qh, bf16* __restrict__ Ql,
    bf16* __restrict__ Kb, bf16* __restrict__ Vt)
{
  // XCD swizzle: 512 wgs = 8 XCDs x 64; each XCD gets 4 m-tiles x 16 n-tiles
  const int swz = ((int)blockIdx.x & 7) * 64 + ((int)blockIdx.x >> 3);
  const int m0 = (swz >> 4) * 128;
  const int n0 = (swz & 15) * 64;
  const int tid = threadIdx.x;
  const int l = tid & 63, w = tid >> 6;
  const int cl = l & 15, g = l >> 4;

  __shared__ __align__(16) bf16 AhS[2][4096];     // [128 m][32 k], swz chunks
  __shared__ __align__(16) bf16 AlS[2][4096];
  __shared__ __align__(16) bf16 WS[2][3][2048];   // [64 n][32 k], swz chunks

  // staging source offsets (inverse-swizzled; dest is linear)
  const int r0 = tid >> 2;                        // 0..63
  const int csw = (((tid & 3) ^ (r0 & 3)) << 3);  // swizzled k-chunk (elems)
  const size_t aoff0 = (size_t)(m0 + r0) * HID_ + csw;
  const size_t aoff1 = (size_t)(m0 + 64 + r0) * HID_ + csw;
  const size_t woff  = (size_t)(n0 + r0) * HID_ + csw;
  const int wb = w * 512;                         // wave's dest slice (elems)

  // fragment read offsets (swizzled)
  const int rA0 = w * 16 + cl;
  const int eA0 = rA0 * 32 + 8 * (g ^ (rA0 & 3));
  const int eA1 = eA0 + 2048;                     // row +64: same swz (64%4==0)
  const int eW  = cl * 32 + 8 * (g ^ (cl & 3));   // + nf*512 (16%4==0)

  f32x4 acc[2][3][4];
#pragma unroll
  for (int hf = 0; hf < 2; ++hf)
#pragma unroll
    for (int s = 0; s < 3; ++s)
#pragma unroll
      for (int nf = 0; nf < 4; ++nf)
#pragma unroll
        for (int i = 0; i < 4; ++i) acc[hf][s][nf][i] = 0.f;

  // prologue: stage kt=0 into buf0
  gload16(Ahg + aoff0, &AhS[0][wb]);
  gload16(Ahg + aoff1, &AhS[0][2048 + wb]);
  gload16(Alg + aoff0, &AlS[0][wb]);
  gload16(Alg + aoff1, &AlS[0][2048 + wb]);
  gload16(Wbg + woff,           &WS[0][0][wb]);
  gload16(Wbg + 1048576 + woff, &WS[0][1][wb]);
  gload16(Wbg + 2097152 + woff, &WS[0][2][wb]);
  __syncthreads();

  int cur = 0;
  for (int kt = 0; kt < HID_ / 32; ++kt) {
    // issue next-tile stage (lands before the barrier below)
    if (kt + 1 < HID_ / 32) {
      const size_t ko = (size_t)(kt + 1) * 32;
      bf16* ah = &AhS[cur ^ 1][0]; bf16* al = &AlS[cur ^ 1][0];
      gload16(Ahg + aoff0 + ko, ah + wb);
      gload16(Ahg + aoff1 + ko, ah + 2048 + wb);
      gload16(Alg + aoff0 + ko, al + wb);
      gload16(Alg + aoff1 + ko, al + 2048 + wb);
      gload16(Wbg + woff + ko,           &WS[cur ^ 1][0][wb]);
      gload16(Wbg + 1048576 + woff + ko, &WS[cur ^ 1][1][wb]);
      gload16(Wbg + 2097152 + woff + ko, &WS[cur ^ 1][2][wb]);
    }

    const bf16x8 fah0 = *(const bf16x8*)&AhS[cur][eA0];
    const bf16x8 fah1 = *(const bf16x8*)&AhS[cur][eA1];
    const bf16x8 fal0 = *(const bf16x8*)&AlS[cur][eA0];
    const bf16x8 fal1 = *(const bf16x8*)&AlS[cur][eA1];
#pragma unroll
    for (int s = 0; s < 3; ++s)
#pragma unroll
      for (int nf = 0; nf < 4; ++nf) {
        const bf16x8 fb = *(const bf16x8*)&WS[cur][s][nf * 512 + eW];
        acc[0][s][nf] = mfma16(fah0, fb, acc[0][s][nf]);
        acc[0][s][nf] = mfma16(fal0, fb, acc[0][s][nf]);
        acc[1][s][nf] = mfma16(fah1, fb, acc[1][s][nf]);
        acc[1][s][nf] = mfma16(fal1, fb, acc[1][s][nf]);
      }
    __syncthreads();   // drains this wave's gloads (next buf ready) + read fence
    cur ^= 1;
  }

  const float* bs_[3] = {bq, bk, bv};
#pragma unroll
  for (int s = 0; s < 3; ++s)
#pragma unroll
    for (int nf = 0; nf < 4; ++nf) {
      const int n = n0 + nf * 16 + cl;
      const float bias = bs_[s][n];
      const int hd = n >> 6, d = n & 63;
#pragma unroll
      for (int hf = 0; hf < 2; ++hf)
#pragma unroll
        for (int reg = 0; reg < 4; ++reg) {
          const int m = m0 + hf * 64 + w * 16 + g * 4 + reg;
          const int b = m >> 11, sq = m & (S_ - 1);
          const float val = acc[hf][s][nf][reg] + bias;
          if (s == 0) {
            bf16 h, o; split2(val * QSC_, h, o);
            const size_t idx = ((size_t)(b * H_ + hd) * S_ + sq) * D_ + d;
            Qh[idx] = h; Ql[idx] = o;
          } else if (s == 1) {
            Kb[((size_t)(b * H_ + hd) * S_ + sq) * D_ + d] = (bf16)val;
          } else {
            Vt[(((size_t)(b * H_ + hd) * (S_ / 32) + (sq >> 5)) * D_ + d) * 32 + (sq & 31)]
                = (bf16)val;
          }
        }
    }
}

// ---------------- attention v8 (unchanged, passed r8): 8 waves / 64 q-rows,
// LDS K/V double-buffer via global_load_lds, swizzled, 2 barriers/kt.
__global__ __launch_bounds__(512, 4) void attn_kernel(
    const bf16* __restrict__ Qh, const bf16* __restrict__ Ql,
    const bf16* __restrict__ Kb, const bf16* __restrict__ Vt,
    const float* __restrict__ msk2, const bf16* __restrict__ rkEb,
    const bf16* __restrict__ rvTb, float* __restrict__ out)
{
  const int swz = ((int)blockIdx.x & 7) * 128 + ((int)blockIdx.x >> 3);
  const int qt = swz & 31, h = (swz >> 5) & 15, b = swz >> 9;
  const int q0 = qt * 64;
  const int tid = threadIdx.x;
  const int l = tid & 63, w = tid >> 6;
  const int wq = (w & 3) * 16;
  const int wh = w >> 2;
  const int cl = l & 15, g = l >> 4, kg8 = g * 8;
  const int lq = wq + cl;

  __shared__ __align__(16) bf16 k_s[2][4096];
  __shared__ __align__(16) bf16 v_s[2][4096];
  __shared__ __align__(16) bf16 T[64][288];
  __shared__ __align__(16) bf16 ph[64][72];
  __shared__ float red[2][3][64];
  __shared__ float lsum_s[64];

  const size_t bh = (size_t)(b * H_ + h) * S_;
  const bf16* Kbase = Kb + bh * D_;
  const bf16* Vbase = Vt + bh * D_;
  const float* mbase = msk2 + b * S_;

  const int tKr = tid >> 3;
  const int koff = tKr * 64 + (((tid & 7) ^ (tKr & 7)) << 3);
  const int tVs = tid >> 8, tVu = tid & 255, tVd = tVu >> 2;
  const int voff = tVs * 2048 + tVd * 32 + ((((tVu & 3) ^ (tVd & 3))) << 3);
  bf16* kdst0 = &k_s[0][w * 512]; bf16* kdst1 = &k_s[1][w * 512];
  bf16* vdst0 = &v_s[0][w * 512]; bf16* vdst1 = &v_s[1][w * 512];

  gload16(Kbase + koff, kdst0);
  gload16(Vbase + voff, vdst0);

  bf16x8 qh0, qh1, ql0, ql1;
  {
    const size_t base = (bh + q0 + lq) * D_ + kg8;
    qh0 = *(const bf16x8*)(Qh + base);
    qh1 = *(const bf16x8*)(Qh + base + 32);
    ql0 = *(const bf16x8*)(Ql + base);
    ql1 = *(const bf16x8*)(Ql + base + 32);
  }

  {
    const int nt0 = wh ? 9 : 0, ntE = wh ? 17 : 9;
    for (int nt = nt0; nt < ntE; ++nt) {
      f32x4 r; r[0] = r[1] = r[2] = r[3] = 0.f;
      const bf16x8 a0 = *(const bf16x8*)(rkEb + (size_t)(nt * 16 + cl) * 64 + kg8);
      const bf16x8 a1 = *(const bf16x8*)(rkEb + (size_t)(nt * 16 + cl) * 64 + 32 + kg8);
      r = mfma16(a0, qh0, r); r = mfma16(a0, ql0, r);
      r = mfma16(a1, qh1, r); r = mfma16(a1, ql1, r);
      bf16x4 pk;
#pragma unroll
      for (int reg = 0; reg < 4; ++reg) pk[reg] = (bf16)r[reg];
      *(bf16x4*)&T[lq][nt * 16 + g * 4] = pk;
    }
  }
  __syncthreads();

  const float rs_lo = (float)T[lq][0];
  const float rs_hi = (float)T[lq][2 * R_];
  const int qg = q0 + lq;

  f32x4 ctx0, ctx1;
#pragma unroll
  for (int i = 0; i < 4; ++i) { ctx0[i] = 0.f; ctx1[i] = 0.f; }
  float lsum = 0.f, plo = 0.f, phi = 0.f;

  const int r00 = wh * 32 + cl, r10 = wh * 32 + 16 + cl;
  const int ksw = (r00 & 7);
  const int rd0 = wh * 32 + cl, rd1 = wh * 32 + 16 + cl;
  const int vsw = (rd0 & 3);
  const int e00 = r00 * 64 + 8 * (g ^ ksw),  e01 = r00 * 64 + 8 * ((4 + g) ^ ksw);
  const int e10 = r10 * 64 + 8 * (g ^ ksw),  e11 = r10 * 64 + 8 * ((4 + g) ^ ksw);
  const int f0 = rd0 * 32 + 8 * (g ^ vsw),   f1 = rd1 * 32 + 8 * (g ^ vsw);

  int cur = 0;
  for (int kt = 0; kt < S_ / 64; ++kt) {
    if (kt + 1 < S_ / 64) {
      gload16(Kbase + (size_t)(kt + 1) * 4096 + koff, cur ? kdst0 : kdst1);
      gload16(Vbase + (size_t)(kt + 1) * 4096 + voff, cur ? vdst0 : vdst1);
    }

    const bf16* kc = &k_s[cur][0];
    const bf16x8 a00 = *(const bf16x8*)&kc[e00];
    const bf16x8 a01 = *(const bf16x8*)&kc[e01];
    const bf16x8 a10 = *(const bf16x8*)&kc[e10];
    const bf16x8 a11 = *(const bf16x8*)&kc[e11];

    f32x4 s0, s1;
    s0[0]=s0[1]=s0[2]=s0[3]=0.f; s1[0]=s1[1]=s1[2]=s1[3]=0.f;
    s0 = mfma16(a00, qh0, s0); s0 = mfma16(a00, ql0, s0);
    s0 = mfma16(a01, qh1, s0); s0 = mfma16(a01, ql1, s0);
    s1 = mfma16(a10, qh0, s1); s1 = mfma16(a10, ql0, s1);
    s1 = mfma16(a11, qh1, s1); s1 = mfma16(a11, ql1, s1);

    const int j0 = kt * 64 + wh * 32;
    const float4 mk0 = *(const float4*)(mbase + j0 + g * 4);
    const float4 mk1 = *(const float4*)(mbase + j0 + 16 + g * 4);
    const int dlt = kt * 64 - q0;
    const int mode = (dlt <= -192) ? 0 : (dlt >= 192 ? 1 : 2);

#pragma unroll
    for (int nf = 0; nf < 2; ++nf) {
      const f32x4 sa = nf ? s1 : s0;
      const float4 mkv = nf ? mk1 : mk0;
      const float mks[4] = {mkv.x, mkv.y, mkv.z, mkv.w};
      float p[4];
      if (mode == 0) {
#pragma unroll
        for (int reg = 0; reg < 4; ++reg) p[reg] = exp2f(sa[reg] + rs_lo + mks[reg]);
        plo += (p[0] + p[1]) + (p[2] + p[3]);
      } else if (mode == 1) {
#pragma unroll
        for (int reg = 0; reg < 4; ++reg) p[reg] = exp2f(sa[reg] + rs_hi + mks[reg]);
        phi += (p[0] + p[1]) + (p[2] + p[3]);
      } else {
        const int jb = j0 + nf * 16 + g * 4;
#pragma unroll
        for (int reg = 0; reg < 4; ++reg) {
          const int bkv = jb + reg - qg + R_;
          const int bkc = bkv < 0 ? 0 : (bkv > 2 * R_ ? 2 * R_ : bkv);
          const float pv = exp2f(sa[reg] + (float)T[lq][bkc] + mks[reg]);
          p[reg] = pv;
          if (bkv <= 0)           plo += pv;
          else if (bkv >= 2 * R_) phi += pv;
          else                    T[lq][bkv] = (bf16)pv;
        }
      }
      lsum += (p[0] + p[1]) + (p[2] + p[3]);
      bf16x4 pk;
#pragma unroll
      for (int reg = 0; reg < 4; ++reg) pk[reg] = (bf16)p[reg];
      *(bf16x4*)&ph[lq][wh * 32 + nf * 16 + g * 4] = pk;
    }
    __syncthreads();

    const bf16x8 pa0 = *(const bf16x8*)&ph[lq][kg8];
    const bf16x8 pa1 = *(const bf16x8*)&ph[lq][32 + kg8];
    const bf16* vc = &v_s[cur][0];
    const bf16x8 vb00 = *(const bf16x8*)&vc[f0];
    const bf16x8 vb01 = *(const bf16x8*)&vc[2048 + f0];
    const bf16x8 vb10 = *(const bf16x8*)&vc[f1];
    const bf16x8 vb11 = *(const bf16x8*)&vc[2048 + f1];
    ctx0 = mfma16(pa0, vb00, ctx0); ctx0 = mfma16(pa1, vb01, ctx0);
    ctx1 = mfma16(pa0, vb10, ctx1); ctx1 = mfma16(pa1, vb11, ctx1);
    __syncthreads();
    cur ^= 1;
  }

  lsum += __shfl_xor(lsum, 16); lsum += __shfl_xor(lsum, 32);
  plo  += __shfl_xor(plo, 16);  plo  += __shfl_xor(plo, 32);
  phi  += __shfl_xor(phi, 16);  phi  += __shfl_xor(phi, 32);
  if (l < 16) {
    red[wh][0][wq + l] = lsum;
    red[wh][1][wq + l] = plo;
    red[wh][2][wq + l] = phi;
  }
  __syncthreads();
  if (tid < 64) {
    lsum_s[tid]    = red[0][0][tid] + red[1][0][tid];
    T[tid][0]      = (bf16)(red[0][1][tid] + red[1][1][tid]);
    T[tid][2 * R_] = (bf16)(red[0][2][tid] + red[1][2][tid]);
  }
  for (int t = tid; t < 64 * 32; t += 512) {
    const int c = t & 31;
    if (c) T[t >> 5][256 + c] = (bf16)0.f;
  }
  if (q0 < R_ || q0 > S_ - R_ - 64) {
    for (int t = tid; t < 64 * 256; t += 512) {
      const int r = t >> 8, c = t & 255;
      if (c >= 1) {
        const int j = q0 + r + c - R_;
        if (j < 0 || j >= S_) T[r][c] = (bf16)0.f;
      }
    }
  }
  __syncthreads();

#pragma unroll
  for (int ks = 0; ks < 9; ++ks) {
    const bf16x8 pa = *(const bf16x8*)&T[lq][ks * 32 + kg8];
    const bf16x8 v0 = *(const bf16x8*)(rvTb + (size_t)(wh * 32 + cl) * 288 + ks * 32 + kg8);
    const bf16x8 v1 = *(const bf16x8*)(rvTb + (size_t)(wh * 32 + 16 + cl) * 288 + ks * 32 + kg8);
    ctx0 = mfma16(pa, v0, ctx0);
    ctx1 = mfma16(pa, v1, ctx1);
  }

#pragma unroll
  for (int reg = 0; reg < 4; ++reg) {
    const int qrow = wq + g * 4 + reg;
    const float invl = 1.f / lsum_s[qrow];
    float* op = out + (size_t)(b * S_ + q0 + qrow) * HID_ + h * 64 + wh * 32;
    op[cl]      = ctx0[reg] * invl;
    op[16 + cl] = ctx1[reg] * invl;
  }
}

extern "C" void kernel_launch(void* const* d_in, const int* in_sizes, int n_in,
                              void* d_out, int out_size, void* d_ws, size_t ws_size,
                              hipStream_t stream)
{
  (void)in_sizes; (void)n_in; (void)out_size; (void)ws_size;
  const float* hidden  = (const float*)d_in[0];
  const float* st_mask = (const float*)d_in[1];
  const float* Wq = (const float*)d_in[2];
  const float* bq = (const float*)d_in[3];
  const float* Wk = (const float*)d_in[4];
  const float* bk = (const float*)d_in[5];
  const float* Wv = (const float*)d_in[6];
  const float* bv = (const float*)d_in[7];
  const float* rkE = (const float*)d_in[8];
  const float* rvE = (const float*)d_in[9];
  float* out = (float*)d_out;

  const size_t per = (size_t)B_ * H_ * S_ * D_;   // 4,194,304 elements
  bf16* Qh   = (bf16*)d_ws;
  bf16* Ql   = Qh + per;
  bf16* Kb   = Ql + per;
  bf16* Vt   = Kb + per;
  bf16* Ahg  = Vt + per;                  // 4096*1024
  bf16* Alg  = Ahg + per;                 // 4096*1024
  bf16* Wbg  = Alg + per;                 // 3*1024*1024
  bf16* rkEb = Wbg + 3 * 1048576;         // 272*64
  bf16* rvTb = rkEb + 272 * 64;           // 64*288
  float* msk2 = (float*)(rvTb + 64 * 288);

  prep_kernel<<<dim3(1024), 256, 0, stream>>>(
      st_mask, rkE, rvE, hidden, Wq, Wk, Wv, msk2, rkEb, rvTb, Ahg, Alg, Wbg);
  qkv_mfma_kernel<<<dim3(512), 256, 0, stream>>>(
      Ahg, Alg, Wbg, bq, bk, bv, Qh, Ql, Kb, Vt);
  attn_kernel<<<dim3(1024), 512, 0, stream>>>(
      Qh, Ql, Kb, Vt, msk2, rkEb, rvTb, out);
}